// Round 2
// baseline (416.648 us; speedup 1.0000x reference)
//
#include <hip/hip_runtime.h>
#include <math.h>

#define N_ROWS 32768
#define DIM    1024
#define NE     64
#define KTOP   8
#define RW     8              // rows per wave
#define WPB    4              // waves per block (256 threads)
#define RPB    (RW * WPB)     // 32 rows per block

// Pack gate_w[e][k] -> wt4[k>>2][e][k&3] so that a wave (lane=expert) reads
// w[k..k+3][lane] as ONE coalesced global_load_dwordx4 (1 KB/wave/instr).
extern "C" __global__ void transpose_w(const float* __restrict__ gw,
                                       float* __restrict__ wt4) {
    int e = blockIdx.x;                    // 64 blocks
    int t = threadIdx.x;                   // 256 threads, one float4 each
    float4 v = *(const float4*)&gw[e * DIM + t * 4];   // coalesced read
    *(float4*)&wt4[t * (NE * 4) + e * 4] = v;          // wt4[k4][e][0..3]
}

extern "C" __global__ void __launch_bounds__(256, 4)
moe_gate_kernel(const float* __restrict__ x, const float* __restrict__ wt4,
                const float* __restrict__ nw, const float* __restrict__ noise,
                float* __restrict__ out0, float* __restrict__ out1,
                double* __restrict__ esum) {
    const int tid  = threadIdx.x;
    const int lane = tid & 63;                                   // lane = expert
    const int wid  = __builtin_amdgcn_readfirstlane(tid >> 6);   // wave id (uniform)
    const int row0 = blockIdx.x * RPB + wid * RW;                // uniform row base

    float acc[RW];
#pragma unroll
    for (int r = 0; r < RW; ++r) acc[r] = 0.f;

    // ---- GEMM: acc[r] (lane e) = sum_k x[row0+r][k] * w[e][k] ----
    // x loads are wave-uniform (scalar path); w loads are one dwordx4 per 4k.
    const float4* wp = (const float4*)wt4;
#pragma unroll 4
    for (int k4 = 0; k4 < DIM / 4; ++k4) {
        const float4 w = wp[k4 * NE + lane];
#pragma unroll
        for (int r = 0; r < RW; ++r) {
            const float4 xv = ((const float4*)(x + (size_t)(row0 + r) * DIM))[k4];
            acc[r] = fmaf(xv.x, w.x, acc[r]);
            acc[r] = fmaf(xv.y, w.y, acc[r]);
            acc[r] = fmaf(xv.z, w.z, acc[r]);
            acc[r] = fmaf(xv.w, w.w, acc[r]);
        }
    }

    // ---- epilogue: acc[r] is already logits[row][expert=lane] ----
    const float nwl = nw[lane];
    float epart = 0.f;                     // sum of dense gate weights, this expert

#pragma unroll 1
    for (int r = 0; r < RW; ++r) {
        const size_t grow = (size_t)(row0 + r);
        const float  lg   = acc[r];

        // dense softmax over 64 experts (load-balance mean term)
        float m = lg;
#pragma unroll
        for (int off = 32; off; off >>= 1) m = fmaxf(m, __shfl_xor(m, off));
        float p = __expf(lg - m);
        float s = p;
#pragma unroll
        for (int off = 32; off; off >>= 1) s += __shfl_xor(s, off);
        epart += p / s;

        // noisy logits + iterative top-8 argmax (tie -> lower index, jax semantics)
        const float nz    = noise[grow * NE + lane];
        const float noisy = fmaf(nz, nwl, lg);
        float cur  = noisy;
        bool  sel  = false;
        float mtop = 0.f;
        int   myid = 0;
#pragma unroll
        for (int j = 0; j < KTOP; ++j) {
            float v = cur; int id = lane;
#pragma unroll
            for (int off = 32; off; off >>= 1) {
                float ov = __shfl_xor(v, off);
                int   oi = __shfl_xor(id, off);
                if (ov > v || (ov == v && oi < id)) { v = ov; id = oi; }
            }
            if (j == 0) mtop = v;
            if (lane == id) { sel = true; cur = -INFINITY; }
            if (lane == j) myid = id;
        }

        float swv  = sel ? __expf(noisy - mtop) : 0.f;
        float ssum = swv;
#pragma unroll
        for (int off = 32; off; off >>= 1) ssum += __shfl_xor(ssum, off);

        out0[grow * NE + lane] = swv / ssum;                 // coalesced 256 B/row
        if (lane < KTOP) out1[grow * KTOP + lane] = (float)myid;
    }

    // per-block expert partial -> one double atomic per expert per block
    __shared__ float red[WPB * NE];
    red[tid] = epart;
    __syncthreads();
    if (tid < NE) {
        float t = red[tid] + red[NE + tid] + red[2 * NE + tid] + red[3 * NE + tid];
        atomicAdd(&esum[tid], (double)t);
    }
}

extern "C" __global__ void moe_loss_kernel(const double* __restrict__ esum,
                                           float* __restrict__ lossp) {
    int e = threadIdx.x;                   // 64 threads = 1 wave
    double mean = esum[e] * (1.0 / 32768.0);
    double d = mean - (1.0 / 64.0);
    double sq = d * d;
#pragma unroll
    for (int off = 32; off; off >>= 1) sq += __shfl_xor(sq, off);
    if (e == 0) lossp[0] = (float)(sq * (1.0 / 64.0) * 0.01);
}

extern "C" void kernel_launch(void* const* d_in, const int* in_sizes, int n_in,
                              void* d_out, int out_size, void* d_ws, size_t ws_size,
                              hipStream_t stream) {
    const float* x     = (const float*)d_in[0];   // [32768,1024]
    const float* gw    = (const float*)d_in[1];   // [64,1024]
    const float* nw    = (const float*)d_in[2];   // [64]
    const float* noise = (const float*)d_in[3];   // [32768,64]

    float* out0  = (float*)d_out;                       // [32768,64] gated weights
    float* out1  = out0 + (size_t)N_ROWS * NE;          // [32768,8] ids as f32
    float* lossp = out1 + (size_t)N_ROWS * KTOP;        // scalar loss

    double* esum = (double*)d_ws;                       // [64] expert sums
    float*  wt4  = (float*)((char*)d_ws + 512);         // [1024/4][64][4] = 256 KB

    hipMemsetAsync(d_ws, 0, NE * sizeof(double), stream);
    transpose_w<<<NE, 256, 0, stream>>>(gw, wt4);
    moe_gate_kernel<<<N_ROWS / RPB, 256, 0, stream>>>(x, wt4, nw, noise, out0, out1, esum);
    moe_loss_kernel<<<1, 64, 0, stream>>>(esum, lossp);
}

// Round 3
// 368.730 us; speedup vs baseline: 1.1300x; 1.1300x over previous
//
#include <hip/hip_runtime.h>
#include <math.h>

#define N_ROWS 32768
#define DIM    1024
#define NE     64
#define KTOP   8

// Block: 512 threads = 8 waves; 64 rows per block (lane = row).
// Wave w computes partial logits over k in [128w, 128w+128) for ALL 64 experts
// (acc[64] VGPRs/lane). w (gate_w, 256 KB, L2-hot) feeds via s_load broadcast;
// x streams per-lane via VMEM. Zero LDS / barriers in the hot loop.
extern "C" __global__ void __launch_bounds__(512, 4)
moe_gate_kernel(const float* __restrict__ x, const float* __restrict__ gw,
                const float* __restrict__ nw, const float* __restrict__ noise,
                float* __restrict__ out0, float* __restrict__ out1,
                float* __restrict__ lossp,
                double* __restrict__ esum, int* __restrict__ ticket) {
    __shared__ float red[8 * 577];     // padded k-split reduction buffer (18.5 KB)
    __shared__ float lg[64 * 65];      // logits, stride-65 (16.6 KB)
    __shared__ int   isLast;

    const int tid   = threadIdx.x;
    const int lane  = tid & 63;
    const int wid   = __builtin_amdgcn_readfirstlane(tid >> 6);   // 0..7, uniform
    const int row0  = blockIdx.x * 64;
    const int kbase = wid * 128;                                  // uniform k-range

    float acc[NE];
#pragma unroll
    for (int e = 0; e < NE; ++e) acc[e] = 0.f;

    const float* xr = x + (size_t)(row0 + lane) * DIM + kbase;    // per-lane (VMEM)
    const float* wb = gw + kbase;                                 // uniform (SMEM)

    float xv[16], xn[16];
#pragma unroll
    for (int i = 0; i < 4; ++i) *(float4*)(xv + 4 * i) = *(const float4*)(xr + 4 * i);

#pragma unroll 1
    for (int kb = 0; kb < 8; ++kb) {
        if (kb < 7) {                  // prefetch next 16 k's of x (VMEM, in flight)
            const float* xp = xr + (kb + 1) * 16;
#pragma unroll
            for (int i = 0; i < 4; ++i) *(float4*)(xn + 4 * i) = *(const float4*)(xp + 4 * i);
        }
        const float* wk = wb + kb * 16;        // uniform base; e*1024+j are imm offsets
#pragma unroll
        for (int e = 0; e < NE; ++e)
#pragma unroll
            for (int j = 0; j < 16; ++j)
                acc[e] = fmaf(wk[e * DIM + j], xv[j], acc[e]);
#pragma unroll
        for (int i = 0; i < 16; ++i) xv[i] = xn[i];
    }

    // ---- k-split reduction: sum acc over the 8 waves, transpose into lg ----
#pragma unroll
    for (int ec = 0; ec < 8; ++ec) {
#pragma unroll
        for (int j = 0; j < 8; ++j) red[wid * 577 + lane * 9 + j] = acc[ec * 8 + j];
        __syncthreads();
        {
            const int r = tid & 63, j = tid >> 6;
            float s = 0.f;
#pragma unroll
            for (int w = 0; w < 8; ++w) s += red[w * 577 + r * 9 + j];
            lg[r * 65 + ec * 8 + j] = s;
        }
        __syncthreads();
    }

    // ---- epilogue: wave handles 8 rows, lane = expert (round-2 proven code) ----
    const float nwl = nw[lane];
    float epart = 0.f;

#pragma unroll 1
    for (int i = 0; i < 8; ++i) {
        const int    lrow = wid * 8 + i;
        const size_t grow = (size_t)(row0 + lrow);
        const float  lgv  = lg[lrow * 65 + lane];

        // dense softmax over 64 experts (load-balance mean term)
        float m = lgv;
#pragma unroll
        for (int off = 32; off; off >>= 1) m = fmaxf(m, __shfl_xor(m, off));
        float p = __expf(lgv - m);
        float s = p;
#pragma unroll
        for (int off = 32; off; off >>= 1) s += __shfl_xor(s, off);
        epart += p / s;

        // noisy logits + iterative top-8 argmax (tie -> lower index)
        const float nz    = noise[grow * NE + lane];
        const float noisy = fmaf(nz, nwl, lgv);
        float cur  = noisy;
        bool  sel  = false;
        float mtop = 0.f;
        int   myid = 0;
#pragma unroll
        for (int j = 0; j < KTOP; ++j) {
            float v = cur; int id = lane;
#pragma unroll
            for (int off = 32; off; off >>= 1) {
                float ov = __shfl_xor(v, off);
                int   oi = __shfl_xor(id, off);
                if (ov > v || (ov == v && oi < id)) { v = ov; id = oi; }
            }
            if (j == 0) mtop = v;
            if (lane == id) { sel = true; cur = -INFINITY; }
            if (lane == j) myid = id;
        }

        float swv  = sel ? __expf(noisy - mtop) : 0.f;
        float ssum = swv;
#pragma unroll
        for (int off = 32; off; off >>= 1) ssum += __shfl_xor(ssum, off);

        out0[grow * NE + lane] = swv / ssum;                // coalesced 256 B/row
        if (lane < KTOP) out1[grow * KTOP + lane] = (float)myid;
    }

    // ---- load-balance sums: block partial -> device atomics ----
    __syncthreads();                   // lg/red reads done; reuse red
    red[wid * 64 + lane] = epart;
    __syncthreads();
    if (tid < NE) {
        float t = 0.f;
#pragma unroll
        for (int w = 0; w < 8; ++w) t += red[w * 64 + tid];
        atomicAdd(&esum[tid], (double)t);
        __threadfence();
    }
    __syncthreads();
    if (tid == 0) {
        int t = atomicAdd(ticket, 1);
        isLast = (t == (int)gridDim.x - 1);
        __threadfence();
    }
    __syncthreads();

    // ---- last block computes the scalar loss (f64) ----
    if (isLast && tid < NE) {
        double v = atomicAdd(&esum[tid], 0.0);    // device-scope read
        double mean = v * (1.0 / 32768.0);
        double d  = mean - (1.0 / 64.0);
        double sq = d * d;
#pragma unroll
        for (int off = 32; off; off >>= 1) sq += __shfl_xor(sq, off);
        if (tid == 0) lossp[0] = (float)(sq * (1.0 / 64.0) * 0.01);
    }
}

extern "C" void kernel_launch(void* const* d_in, const int* in_sizes, int n_in,
                              void* d_out, int out_size, void* d_ws, size_t ws_size,
                              hipStream_t stream) {
    const float* x     = (const float*)d_in[0];   // [32768,1024]
    const float* gw    = (const float*)d_in[1];   // [64,1024]
    const float* nw    = (const float*)d_in[2];   // [64]
    const float* noise = (const float*)d_in[3];   // [32768,64]

    float* out0  = (float*)d_out;                       // [32768,64] gated weights
    float* out1  = out0 + (size_t)N_ROWS * NE;          // [32768,8] ids as f32
    float* lossp = out1 + (size_t)N_ROWS * KTOP;        // scalar loss

    double* esum   = (double*)d_ws;                     // [64]
    int*    ticket = (int*)((char*)d_ws + 512);

    hipMemsetAsync(d_ws, 0, 520, stream);
    moe_gate_kernel<<<N_ROWS / 64, 512, 0, stream>>>(x, gw, nw, noise,
                                                     out0, out1, lossp, esum, ticket);
}